// Round 1
// baseline (2745.278 us; speedup 1.0000x reference)
//
#include <hip/hip_runtime.h>
#include <stdint.h>

typedef __attribute__((ext_vector_type(8))) short bf16x8;
typedef __attribute__((ext_vector_type(4))) float f32x4;

static __device__ __forceinline__ unsigned short f2bf(float f){
  unsigned int u = __float_as_uint(f);
  return (unsigned short)((u + 0x7fffu + ((u >> 16) & 1u)) >> 16);
}

static __device__ __forceinline__ void gld_lds16(const void* g, void* l){
  __builtin_amdgcn_global_load_lds((__attribute__((address_space(1))) void*)(void*)g,
                                   (__attribute__((address_space(3))) void*)l, 16, 0, 0);
}

// ---------------- fp32 -> bf16 conversions ----------------
__global__ void k_f2bf(const float* __restrict__ in, unsigned short* __restrict__ out, int n){
  int i = (blockIdx.x * 256 + threadIdx.x) * 8;
  if (i + 8 <= n){
    float4 a = *(const float4*)(in + i);
    float4 b = *(const float4*)(in + i + 4);
    ushort4 r0 = { f2bf(a.x), f2bf(a.y), f2bf(a.z), f2bf(a.w) };
    ushort4 r1 = { f2bf(b.x), f2bf(b.y), f2bf(b.z), f2bf(b.w) };
    *(ushort4*)(out + i) = r0;
    *(ushort4*)(out + i + 4) = r1;
  } else {
    for (int j = i; j < n; ++j) out[j] = f2bf(in[j]);
  }
}

// pad fc2_w (40x256) into 48x256 bf16, zero rows >= 40
__global__ void k_w2pad(const float* __restrict__ w2, unsigned short* __restrict__ out){
  int e = blockIdx.x * 256 + threadIdx.x;   // grid 48 blocks -> 48*256 elems
  int r = e >> 8, c = e & 255;
  float v = (r < 40) ? w2[r * 256 + c] : 0.f;
  out[e] = f2bf(v);
}

// ---------------- GEMM1: H = relu(X @ W1^T + b1), bf16 in, bf16 out ----------------
// X: M x 512, W1: 256 x 512 (both row-major, K contiguous). 128x128 tile, BK=32.
__global__ __launch_bounds__(256) void k_gemm1(
    const unsigned short* __restrict__ A,   // M x 512 bf16
    const unsigned short* __restrict__ B,   // 256 x 512 bf16
    const float* __restrict__ bias,         // 256 fp32
    unsigned short* __restrict__ H,         // M x 256 bf16
    int M)
{
  __shared__ __align__(16) unsigned short lA[128 * 32];
  __shared__ __align__(16) unsigned short lB[128 * 32];
  const int K = 512;
  int tid = threadIdx.x;
  int wave = tid >> 6, lane = tid & 63;
  int quad = lane >> 4, l16 = lane & 15;
  int rowBase = blockIdx.x * 128;
  int colBase = blockIdx.y * 128;
  int wm = (wave & 1) * 64, wn = (wave >> 1) * 64;

  f32x4 acc[4][4] = {};

  for (int k0 = 0; k0 < K; k0 += 32){
    // stage A and B tiles: 8192 B each = 8 issues of 64 lanes x 16 B; this wave: 2 issues each.
    // 16B-chunk XOR swizzle (slot = chunk ^ (row&3)) to cut ds_read bank conflicts 8-way -> 4-way.
#pragma unroll
    for (int i = 0; i < 2; ++i){
      int issue = wave * 2 + i;
      int s = issue * 64 + lane;        // chunk slot in tile (512 slots)
      int r = s >> 2;                   // tile row
      int c = (s & 3) ^ (r & 3);        // logical 16B chunk within row
      int gr = rowBase + r; if (gr >= M) gr = M - 1;
      gld_lds16(A + (size_t)gr * K + k0 + c * 8, (char*)lA + issue * 1024);
      gld_lds16(B + (size_t)(colBase + r) * K + k0 + c * 8, (char*)lB + issue * 1024);
    }
    __syncthreads();
    bf16x8 af[4], bf[4];
#pragma unroll
    for (int mt = 0; mt < 4; ++mt){
      int r = wm + mt * 16 + l16;
      af[mt] = *(const bf16x8*)&lA[r * 32 + ((quad ^ (r & 3)) * 8)];
    }
#pragma unroll
    for (int nt = 0; nt < 4; ++nt){
      int r = wn + nt * 16 + l16;
      bf[nt] = *(const bf16x8*)&lB[r * 32 + ((quad ^ (r & 3)) * 8)];
    }
#pragma unroll
    for (int mt = 0; mt < 4; ++mt)
#pragma unroll
      for (int nt = 0; nt < 4; ++nt)
        acc[mt][nt] = __builtin_amdgcn_mfma_f32_16x16x32_bf16(af[mt], bf[nt], acc[mt][nt], 0, 0, 0);
    __syncthreads();
  }

#pragma unroll
  for (int nt = 0; nt < 4; ++nt){
    int col = colBase + wn + nt * 16 + l16;
    float bb = bias[col];
#pragma unroll
    for (int mt = 0; mt < 4; ++mt){
#pragma unroll
      for (int rr = 0; rr < 4; ++rr){
        int row = rowBase + wm + mt * 16 + quad * 4 + rr;
        if (row < M){
          float v = acc[mt][nt][rr] + bb;
          v = v > 0.f ? v : 0.f;
          H[(size_t)row * 256 + col] = f2bf(v);
        }
      }
    }
  }
}

// ---------------- GEMM2: FT = H @ W2^T + b2 (fp32 out, N-dim padded to 48) ----------------
__global__ __launch_bounds__(256) void k_gemm2(
    const unsigned short* __restrict__ H,    // M x 256 bf16
    const unsigned short* __restrict__ W2p,  // 48 x 256 bf16 (rows >= 40 zero)
    const float* __restrict__ b2,            // 40 fp32
    float* __restrict__ ft,                  // M x 40 fp32
    int M)
{
  __shared__ __align__(16) unsigned short lW[48 * 264];  // +8 shorts pad per row: conflict-free
  int tid = threadIdx.x;
  int wave = tid >> 6, lane = tid & 63;
  int quad = lane >> 4, l16 = lane & 15;

  for (int idx = tid; idx < 48 * 32; idx += 256){
    int r = idx >> 5, c = idx & 31;
    *(bf16x8*)&lW[r * 264 + c * 8] = *(const bf16x8*)&W2p[r * 256 + c * 8];
  }
  __syncthreads();

  int row0 = blockIdx.x * 64 + wave * 16;
  f32x4 acc[3] = {};
  int r = row0 + l16; if (r >= M) r = M - 1;   // clamp; OOB rows never stored
#pragma unroll
  for (int ks = 0; ks < 8; ++ks){
    bf16x8 af = *(const bf16x8*)&H[(size_t)r * 256 + ks * 32 + quad * 8];
#pragma unroll
    for (int nt = 0; nt < 3; ++nt){
      bf16x8 bf = *(const bf16x8*)&lW[(nt * 16 + l16) * 264 + ks * 32 + quad * 8];
      acc[nt] = __builtin_amdgcn_mfma_f32_16x16x32_bf16(af, bf, acc[nt], 0, 0, 0);
    }
  }
#pragma unroll
  for (int nt = 0; nt < 3; ++nt){
    int col = nt * 16 + l16;
    if (col < 40){
      float bb = b2[col];
#pragma unroll
      for (int rr = 0; rr < 4; ++rr){
        int row = row0 + quad * 4 + rr;
        if (row < M) ft[(size_t)row * 40 + col] = acc[nt][rr] + bb;
      }
    }
  }
}

// ---------------- graph prep ----------------
__global__ void k_initdeg(int* __restrict__ deg, int* __restrict__ cnt, int n){
  int i = blockIdx.x * 256 + threadIdx.x;
  if (i < n){ deg[i] = 1; cnt[i] = 1; }    // self-loop contributes 1 to both
}
__global__ void k_count(const int* __restrict__ ei, int E, int* __restrict__ deg, int* __restrict__ cnt){
  int e = blockIdx.x * 256 + threadIdx.x;
  if (e < E){
    atomicAdd(&deg[ei[e]], 1);        // row occurrences
    atomicAdd(&cnt[ei[E + e]], 1);    // col occurrences (CSC sizing)
  }
}
__global__ void k_dis(const int* __restrict__ deg, float* __restrict__ dis, int n){
  int i = blockIdx.x * 256 + threadIdx.x;
  if (i < n) dis[i] = rsqrtf((float)deg[i]);
}

// exclusive scan over counts: per-1024-elem blocks
__global__ void k_scan1(const int* __restrict__ cnt, int* __restrict__ out, int* __restrict__ bsum, int n){
  __shared__ int ts[256];
  int tid = threadIdx.x;
  int base = blockIdx.x * 1024 + tid * 4;
  int v0 = (base     < n) ? cnt[base]     : 0;
  int v1 = (base + 1 < n) ? cnt[base + 1] : 0;
  int v2 = (base + 2 < n) ? cnt[base + 2] : 0;
  int v3 = (base + 3 < n) ? cnt[base + 3] : 0;
  int tot = v0 + v1 + v2 + v3;
  ts[tid] = tot; __syncthreads();
  int val = tot;
  for (int d = 1; d < 256; d <<= 1){
    int t = (tid >= d) ? ts[tid - d] : 0;
    __syncthreads();
    val += t; ts[tid] = val;
    __syncthreads();
  }
  int ex = val - tot;
  if (base     < n) out[base]     = ex;
  if (base + 1 < n) out[base + 1] = ex + v0;
  if (base + 2 < n) out[base + 2] = ex + v0 + v1;
  if (base + 3 < n) out[base + 3] = ex + v0 + v1 + v2;
  if (tid == 255) bsum[blockIdx.x] = val;
}
__global__ void k_scan2(int* __restrict__ bsum, int nb, int* __restrict__ offN){
  __shared__ int ts[256];
  int tid = threadIdx.x;
  int v = (tid < nb) ? bsum[tid] : 0;
  ts[tid] = v; __syncthreads();
  int val = v;
  for (int d = 1; d < 256; d <<= 1){
    int t = (tid >= d) ? ts[tid - d] : 0;
    __syncthreads();
    val += t; ts[tid] = val;
    __syncthreads();
  }
  if (tid < nb) bsum[tid] = val - v;
  if (tid == 255) *offN = val;   // grand total = E + N
}
__global__ void k_scan3(int* __restrict__ off, const int* __restrict__ bsum, int* __restrict__ cur, int n){
  int base = blockIdx.x * 1024 + threadIdx.x * 4;
  int add = bsum[blockIdx.x];
#pragma unroll
  for (int i = 0; i < 4; ++i){
    int j = base + i;
    if (j < n){ int v = off[j] + add; off[j] = v; cur[j] = v; }
  }
}

__global__ void k_scatter_e(const int* __restrict__ ei, int E, const float* __restrict__ dis,
                            int* __restrict__ cur, int* __restrict__ srcA, float* __restrict__ nrmA){
  int e = blockIdx.x * 256 + threadIdx.x;
  if (e < E){
    int r = ei[e], c = ei[E + e];
    int pos = atomicAdd(&cur[c], 1);
    srcA[pos] = r;
    nrmA[pos] = dis[r] * dis[c];
  }
}
__global__ void k_scatter_s(const float* __restrict__ dis, int* __restrict__ cur,
                            int* __restrict__ srcA, float* __restrict__ nrmA, int n){
  int i = blockIdx.x * 256 + threadIdx.x;
  if (i < n){
    int pos = atomicAdd(&cur[i], 1);
    srcA[pos] = i;
    float d = dis[i];
    nrmA[pos] = d * d;
  }
}

// ---------------- label propagation: wave per node, lanes 0..39 = channels ----------------
__global__ __launch_bounds__(256) void k_prop(
    const int* __restrict__ offs, const int* __restrict__ srcA, const float* __restrict__ nrmA,
    const float* __restrict__ pin, float* __restrict__ pout,
    const int* __restrict__ mask, const float* __restrict__ hard, int n)
{
  int node = blockIdx.x * 4 + (threadIdx.x >> 6);
  int lane = threadIdx.x & 63;
  if (node >= n) return;
  if (mask[node]){
    if (lane < 40) pout[(size_t)node * 40 + lane] = hard[(size_t)node * 40 + lane];
    return;
  }
  if (lane >= 40) return;
  float acc = 0.f;
  int s = offs[node], e = offs[node + 1];
  for (int i = s; i < e; ++i)
    acc = fmaf(nrmA[i], pin[(size_t)srcA[i] * 40 + lane], acc);
  pout[(size_t)node * 40 + lane] = acc;
}

// final step fused with sigmoid gate combine
__global__ __launch_bounds__(256) void k_prop_final(
    const int* __restrict__ offs, const int* __restrict__ srcA, const float* __restrict__ nrmA,
    const float* __restrict__ pin, const int* __restrict__ mask, const float* __restrict__ hard,
    const float* __restrict__ alpha, const float* __restrict__ ft, float* __restrict__ outp, int n)
{
  int node = blockIdx.x * 4 + (threadIdx.x >> 6);
  int lane = threadIdx.x & 63;
  if (node >= n || lane >= 40) return;
  float a = 1.f / (1.f + __expf(-alpha[node]));
  float v;
  if (mask[node]){
    v = hard[(size_t)node * 40 + lane];
  } else {
    float acc = 0.f;
    int s = offs[node], e = offs[node + 1];
    for (int i = s; i < e; ++i)
      acc = fmaf(nrmA[i], pin[(size_t)srcA[i] * 40 + lane], acc);
    v = acc;
  }
  outp[(size_t)node * 40 + lane] = a * v + (1.f - a) * ft[(size_t)node * 40 + lane];
}

extern "C" void kernel_launch(void* const* d_in, const int* in_sizes, int n_in,
                              void* d_out, int out_size, void* d_ws, size_t ws_size,
                              hipStream_t stream)
{
  const float* x     = (const float*)d_in[0];
  const int*   ei    = (const int*)d_in[1];
  const float* linit = (const float*)d_in[2];
  const int*   mask  = (const int*)d_in[3];
  const float* hard  = (const float*)d_in[4];
  const float* w1    = (const float*)d_in[5];
  const float* b1    = (const float*)d_in[6];
  const float* w2    = (const float*)d_in[7];
  const float* b2    = (const float*)d_in[8];
  const float* alpha = (const float*)d_in[9];
  float* out = (float*)d_out;

  const int N   = in_sizes[3];        // 100000
  const int E   = in_sizes[1] / 2;    // 3200000
  const int K1  = in_sizes[0] / N;    // 512
  const int HID = in_sizes[6];        // 256

  char* ws = (char*)d_ws;
  // Region layout (aliased to fit ~170 MB):
  //   [0, N*K1*2)           x_bf16; after GEMM1 done, reused for CSC + graph arrays
  //   [N*K1*2, +N*HID*2)    h_bf16; after GEMM2 done, reused for plp ping-pong
  //   then w1_bf16, w2_pad_bf16, ft
  size_t sXB = (size_t)N * K1 * 2;
  size_t sH  = (size_t)N * HID * 2;
  unsigned short* xb  = (unsigned short*)(ws);
  unsigned short* hb  = (unsigned short*)(ws + sXB);
  unsigned short* w1b = (unsigned short*)(ws + sXB + sH);
  unsigned short* w2p = (unsigned short*)(ws + sXB + sH + (size_t)HID * K1 * 2);
  float*          ft  = (float*)(ws + sXB + sH + (size_t)HID * K1 * 2 + 48 * 256 * 2);
  // CSC aliases over x_bf16 region (used only after GEMM1 consumed xb)
  int*   srcA = (int*)(ws + 0);
  float* nrmA = (float*)(ws + (size_t)(E + N) * 4);
  int*   deg  = (int*)(ws + (size_t)(E + N) * 8);
  int*   cnt  = (int*)(ws + (size_t)(E + N) * 8 + (size_t)N * 4);
  float* dis  = (float*)(ws + (size_t)(E + N) * 8 + (size_t)N * 8);
  int*   offs = (int*)(ws + (size_t)(E + N) * 8 + (size_t)N * 12);
  int*   cur  = (int*)(ws + (size_t)(E + N) * 8 + (size_t)N * 12 + ((size_t)(N + 1) * 4 + 124));
  int*   bsum = (int*)(ws + (size_t)(E + N) * 8 + (size_t)N * 12 + ((size_t)(N + 1) * 4 + 124) + (size_t)N * 4);
  // plp ping-pong aliases over h_bf16 region (used only after GEMM2 consumed hb)
  float* pA = (float*)(ws + sXB);
  float* pB = (float*)(ws + sXB + (size_t)N * 40 * 4);

  // 1) conversions
  k_f2bf<<<(N * K1 / 8 + 255) / 256, 256, 0, stream>>>(x, xb, N * K1);
  k_f2bf<<<(HID * K1 / 8 + 255) / 256, 256, 0, stream>>>(w1, w1b, HID * K1);
  k_w2pad<<<48, 256, 0, stream>>>(w2, w2p);

  // 2) MLP branch
  dim3 g1((N + 127) / 128, HID / 128);
  k_gemm1<<<g1, 256, 0, stream>>>(xb, w1b, b1, hb, N);
  k_gemm2<<<(N + 63) / 64, 256, 0, stream>>>(hb, w2p, b2, ft, N);

  // 3) graph prep (CSC by col)
  k_initdeg<<<(N + 255) / 256, 256, 0, stream>>>(deg, cnt, N);
  k_count<<<(E + 255) / 256, 256, 0, stream>>>(ei, E, deg, cnt);
  k_dis<<<(N + 255) / 256, 256, 0, stream>>>(deg, dis, N);
  int nsb = (N + 1023) / 1024;
  k_scan1<<<nsb, 256, 0, stream>>>(cnt, offs, bsum, N);
  k_scan2<<<1, 256, 0, stream>>>(bsum, nsb, offs + N);
  k_scan3<<<nsb, 256, 0, stream>>>(offs, bsum, cur, N);
  k_scatter_e<<<(E + 255) / 256, 256, 0, stream>>>(ei, E, dis, cur, srcA, nrmA);
  k_scatter_s<<<(N + 255) / 256, 256, 0, stream>>>(dis, cur, srcA, nrmA, N);

  // 4) 10 propagation steps (last fused with combine)
  const float* pin = linit;
  float* pbuf[2] = { pA, pB };
  for (int s = 0; s < 9; ++s){
    float* po = pbuf[s & 1];
    k_prop<<<(N + 3) / 4, 256, 0, stream>>>(offs, srcA, nrmA, pin, po, mask, hard, N);
    pin = po;
  }
  k_prop_final<<<(N + 3) / 4, 256, 0, stream>>>(offs, srcA, nrmA, pin, mask, hard, alpha, ft, out, N);
}

// Round 2
// 1164.917 us; speedup vs baseline: 2.3566x; 2.3566x over previous
//
#include <hip/hip_runtime.h>
#include <stdint.h>

typedef __attribute__((ext_vector_type(8))) short bf16x8;
typedef __attribute__((ext_vector_type(4))) float f32x4;

static __device__ __forceinline__ unsigned short f2bf(float f){
  unsigned int u = __float_as_uint(f);
  return (unsigned short)((u + 0x7fffu + ((u >> 16) & 1u)) >> 16);
}
static __device__ __forceinline__ float bf2f(unsigned short h){
  return __uint_as_float(((unsigned int)h) << 16);
}

static __device__ __forceinline__ void gld_lds16(const void* g, void* l){
  __builtin_amdgcn_global_load_lds((__attribute__((address_space(1))) void*)(void*)g,
                                   (__attribute__((address_space(3))) void*)l, 16, 0, 0);
}

// ---------------- fp32 -> bf16 conversions ----------------
__global__ void k_f2bf(const float* __restrict__ in, unsigned short* __restrict__ out, int n){
  int i = (blockIdx.x * 256 + threadIdx.x) * 8;
  if (i + 8 <= n){
    float4 a = *(const float4*)(in + i);
    float4 b = *(const float4*)(in + i + 4);
    ushort4 r0 = { f2bf(a.x), f2bf(a.y), f2bf(a.z), f2bf(a.w) };
    ushort4 r1 = { f2bf(b.x), f2bf(b.y), f2bf(b.z), f2bf(b.w) };
    *(ushort4*)(out + i) = r0;
    *(ushort4*)(out + i + 4) = r1;
  } else {
    for (int j = i; j < n; ++j) out[j] = f2bf(in[j]);
  }
}

// pad fc2_w (40x256) into 48x256 bf16, zero rows >= 40
__global__ void k_w2pad(const float* __restrict__ w2, unsigned short* __restrict__ out){
  int e = blockIdx.x * 256 + threadIdx.x;
  int r = e >> 8, c = e & 255;
  float v = (r < 40) ? w2[r * 256 + c] : 0.f;
  out[e] = f2bf(v);
}

// ---------------- GEMM1: H = relu(X @ W1^T + b1), bf16 in, bf16 out ----------------
__global__ __launch_bounds__(256) void k_gemm1(
    const unsigned short* __restrict__ A,   // M x 512 bf16
    const unsigned short* __restrict__ B,   // 256 x 512 bf16
    const float* __restrict__ bias,         // 256 fp32
    unsigned short* __restrict__ H,         // M x 256 bf16
    int M)
{
  __shared__ __align__(16) unsigned short lA[128 * 32];
  __shared__ __align__(16) unsigned short lB[128 * 32];
  const int K = 512;
  int tid = threadIdx.x;
  int wave = tid >> 6, lane = tid & 63;
  int quad = lane >> 4, l16 = lane & 15;
  int rowBase = blockIdx.x * 128;
  int colBase = blockIdx.y * 128;
  int wm = (wave & 1) * 64, wn = (wave >> 1) * 64;

  f32x4 acc[4][4] = {};

  for (int k0 = 0; k0 < K; k0 += 32){
#pragma unroll
    for (int i = 0; i < 2; ++i){
      int issue = wave * 2 + i;
      int s = issue * 64 + lane;
      int r = s >> 2;
      int c = (s & 3) ^ (r & 3);
      int gr = rowBase + r; if (gr >= M) gr = M - 1;
      gld_lds16(A + (size_t)gr * K + k0 + c * 8, (char*)lA + issue * 1024);
      gld_lds16(B + (size_t)(colBase + r) * K + k0 + c * 8, (char*)lB + issue * 1024);
    }
    __syncthreads();
    bf16x8 af[4], bf[4];
#pragma unroll
    for (int mt = 0; mt < 4; ++mt){
      int r = wm + mt * 16 + l16;
      af[mt] = *(const bf16x8*)&lA[r * 32 + ((quad ^ (r & 3)) * 8)];
    }
#pragma unroll
    for (int nt = 0; nt < 4; ++nt){
      int r = wn + nt * 16 + l16;
      bf[nt] = *(const bf16x8*)&lB[r * 32 + ((quad ^ (r & 3)) * 8)];
    }
#pragma unroll
    for (int mt = 0; mt < 4; ++mt)
#pragma unroll
      for (int nt = 0; nt < 4; ++nt)
        acc[mt][nt] = __builtin_amdgcn_mfma_f32_16x16x32_bf16(af[mt], bf[nt], acc[mt][nt], 0, 0, 0);
    __syncthreads();
  }

#pragma unroll
  for (int nt = 0; nt < 4; ++nt){
    int col = colBase + wn + nt * 16 + l16;
    float bb = bias[col];
#pragma unroll
    for (int mt = 0; mt < 4; ++mt){
#pragma unroll
      for (int rr = 0; rr < 4; ++rr){
        int row = rowBase + wm + mt * 16 + quad * 4 + rr;
        if (row < M){
          float v = acc[mt][nt][rr] + bb;
          v = v > 0.f ? v : 0.f;
          H[(size_t)row * 256 + col] = f2bf(v);
        }
      }
    }
  }
}

// ---------------- GEMM2: FT = H @ W2^T + b2 (fp32 out) ----------------
__global__ __launch_bounds__(256) void k_gemm2(
    const unsigned short* __restrict__ H,
    const unsigned short* __restrict__ W2p,
    const float* __restrict__ b2,
    float* __restrict__ ft,
    int M)
{
  __shared__ __align__(16) unsigned short lW[48 * 264];
  int tid = threadIdx.x;
  int wave = tid >> 6, lane = tid & 63;
  int quad = lane >> 4, l16 = lane & 15;

  for (int idx = tid; idx < 48 * 32; idx += 256){
    int r = idx >> 5, c = idx & 31;
    *(bf16x8*)&lW[r * 264 + c * 8] = *(const bf16x8*)&W2p[r * 256 + c * 8];
  }
  __syncthreads();

  int row0 = blockIdx.x * 64 + wave * 16;
  f32x4 acc[3] = {};
  int r = row0 + l16; if (r >= M) r = M - 1;
#pragma unroll
  for (int ks = 0; ks < 8; ++ks){
    bf16x8 af = *(const bf16x8*)&H[(size_t)r * 256 + ks * 32 + quad * 8];
#pragma unroll
    for (int nt = 0; nt < 3; ++nt){
      bf16x8 bf = *(const bf16x8*)&lW[(nt * 16 + l16) * 264 + ks * 32 + quad * 8];
      acc[nt] = __builtin_amdgcn_mfma_f32_16x16x32_bf16(af, bf, acc[nt], 0, 0, 0);
    }
  }
#pragma unroll
  for (int nt = 0; nt < 3; ++nt){
    int col = nt * 16 + l16;
    if (col < 40){
      float bb = b2[col];
#pragma unroll
      for (int rr = 0; rr < 4; ++rr){
        int row = row0 + quad * 4 + rr;
        if (row < M) ft[(size_t)row * 40 + col] = acc[nt][rr] + bb;
      }
    }
  }
}

// ---------------- graph prep ----------------
// deg=1 (self), cnt = unmasked ? 1 : 0 (CSC only for unmasked cols), nUn=0
__global__ void k_init0(int* __restrict__ deg, int* __restrict__ cnt,
                        const int* __restrict__ mask, int* __restrict__ nUn, int n){
  int i = blockIdx.x * 256 + threadIdx.x;
  if (i < n){ deg[i] = 1; cnt[i] = mask[i] ? 0 : 1; }
  if (i == 0) *nUn = 0;
}

// 4 edges/thread; deg always, cnt only for unmasked cols
__global__ void k_count(const int* __restrict__ ei, int E, const int* __restrict__ mask,
                        int* __restrict__ deg, int* __restrict__ cnt){
  int e0 = (blockIdx.x * 256 + threadIdx.x) * 4;
  if (e0 + 4 <= E){
    int4 r4 = *(const int4*)(ei + e0);
    int4 c4 = *(const int4*)(ei + E + e0);
    atomicAdd(&deg[r4.x], 1); atomicAdd(&deg[r4.y], 1);
    atomicAdd(&deg[r4.z], 1); atomicAdd(&deg[r4.w], 1);
    if (!mask[c4.x]) atomicAdd(&cnt[c4.x], 1);
    if (!mask[c4.y]) atomicAdd(&cnt[c4.y], 1);
    if (!mask[c4.z]) atomicAdd(&cnt[c4.z], 1);
    if (!mask[c4.w]) atomicAdd(&cnt[c4.w], 1);
  } else {
    for (int e = e0; e < E; ++e){
      atomicAdd(&deg[ei[e]], 1);
      int c = ei[E + e];
      if (!mask[c]) atomicAdd(&cnt[c], 1);
    }
  }
}

// dis, dis^2, and append unmasked nodes to list
__global__ void k_dis(const int* __restrict__ deg, const int* __restrict__ mask,
                      float* __restrict__ dis, float* __restrict__ dis2,
                      int* __restrict__ list, int* __restrict__ nUn, int n){
  int i = blockIdx.x * 256 + threadIdx.x;
  if (i < n){
    float d = rsqrtf((float)deg[i]);
    dis[i] = d; dis2[i] = d * d;
    if (!mask[i]){ int pos = atomicAdd(nUn, 1); list[pos] = i; }
  }
}

// exclusive scan over counts: per-1024-elem blocks
__global__ void k_scan1(const int* __restrict__ cnt, int* __restrict__ out, int* __restrict__ bsum, int n){
  __shared__ int ts[256];
  int tid = threadIdx.x;
  int base = blockIdx.x * 1024 + tid * 4;
  int v0 = (base     < n) ? cnt[base]     : 0;
  int v1 = (base + 1 < n) ? cnt[base + 1] : 0;
  int v2 = (base + 2 < n) ? cnt[base + 2] : 0;
  int v3 = (base + 3 < n) ? cnt[base + 3] : 0;
  int tot = v0 + v1 + v2 + v3;
  ts[tid] = tot; __syncthreads();
  int val = tot;
  for (int d = 1; d < 256; d <<= 1){
    int t = (tid >= d) ? ts[tid - d] : 0;
    __syncthreads();
    val += t; ts[tid] = val;
    __syncthreads();
  }
  int ex = val - tot;
  if (base     < n) out[base]     = ex;
  if (base + 1 < n) out[base + 1] = ex + v0;
  if (base + 2 < n) out[base + 2] = ex + v0 + v1;
  if (base + 3 < n) out[base + 3] = ex + v0 + v1 + v2;
  if (tid == 255) bsum[blockIdx.x] = val;
}
__global__ void k_scan2(int* __restrict__ bsum, int nb, int* __restrict__ offN){
  __shared__ int ts[256];
  int tid = threadIdx.x;
  int v = (tid < nb) ? bsum[tid] : 0;
  ts[tid] = v; __syncthreads();
  int val = v;
  for (int d = 1; d < 256; d <<= 1){
    int t = (tid >= d) ? ts[tid - d] : 0;
    __syncthreads();
    val += t; ts[tid] = val;
    __syncthreads();
  }
  if (tid < nb) bsum[tid] = val - v;
  if (tid == 255) *offN = val;
}
__global__ void k_scan3(int* __restrict__ off, const int* __restrict__ bsum, int* __restrict__ cur, int n){
  int base = blockIdx.x * 1024 + threadIdx.x * 4;
  int add = bsum[blockIdx.x];
#pragma unroll
  for (int i = 0; i < 4; ++i){
    int j = base + i;
    if (j < n){ int v = off[j] + add; off[j] = v; cur[j] = v; }
  }
}

// scatter edges into CSC (unmasked cols only); payload = src index only
__global__ void k_scatter_e(const int* __restrict__ ei, int E, const int* __restrict__ mask,
                            int* __restrict__ cur, int* __restrict__ srcA){
  int e0 = (blockIdx.x * 256 + threadIdx.x) * 4;
  if (e0 + 4 <= E){
    int4 r4 = *(const int4*)(ei + e0);
    int4 c4 = *(const int4*)(ei + E + e0);
    if (!mask[c4.x]){ int p = atomicAdd(&cur[c4.x], 1); srcA[p] = r4.x; }
    if (!mask[c4.y]){ int p = atomicAdd(&cur[c4.y], 1); srcA[p] = r4.y; }
    if (!mask[c4.z]){ int p = atomicAdd(&cur[c4.z], 1); srcA[p] = r4.z; }
    if (!mask[c4.w]){ int p = atomicAdd(&cur[c4.w], 1); srcA[p] = r4.w; }
  } else {
    for (int e = e0; e < E; ++e){
      int c = ei[E + e];
      if (!mask[c]){ int p = atomicAdd(&cur[c], 1); srcA[p] = ei[e]; }
    }
  }
}
__global__ void k_scatter_s(const int* __restrict__ mask, int* __restrict__ cur, int* __restrict__ srcA, int n){
  int i = blockIdx.x * 256 + threadIdx.x;
  if (i < n && !mask[i]){ int pos = atomicAdd(&cur[i], 1); srcA[pos] = i; }
}

// scaled-label buffers: psInit = linit*dis (all nodes);
// masked rows of psA/psB = hard*dis (constant across steps)
__global__ void k_init_ps(const float* __restrict__ linit, const float* __restrict__ hard,
                          const float* __restrict__ dis, const int* __restrict__ mask,
                          unsigned short* __restrict__ psI, unsigned short* __restrict__ psA,
                          unsigned short* __restrict__ psB, int total){
  int i = blockIdx.x * 256 + threadIdx.x;
  if (i >= total) return;
  int node = i / 40;
  float d = dis[node];
  psI[i] = f2bf(linit[i] * d);
  if (mask[node]){
    unsigned short h = f2bf(hard[i] * d);
    psA[i] = h; psB[i] = h;
  }
}

// ---------------- label propagation over unmasked-node list ----------------
// ps_out[c] = dis2[c] * sum_{r in CSC(c)} ps_in[r]   (scaled labels, bf16)
__global__ __launch_bounds__(256) void k_prop(
    const int* __restrict__ offs, const int* __restrict__ srcA,
    const int* __restrict__ list, const int* __restrict__ nUn,
    const float* __restrict__ dis2,
    const unsigned short* __restrict__ pin, unsigned short* __restrict__ pout)
{
  int widx = blockIdx.x * 4 + (threadIdx.x >> 6);
  if (widx >= *nUn) return;
  int node = __builtin_amdgcn_readfirstlane(list[widx]);
  int lane = threadIdx.x & 63;
  if (lane >= 40) return;
  int s = offs[node], e = offs[node + 1];
  float acc0 = 0.f, acc1 = 0.f;
  int i = s;
  for (; i + 4 <= e; i += 4){
    int s0 = srcA[i], s1 = srcA[i + 1], s2 = srcA[i + 2], s3 = srcA[i + 3];
    acc0 += bf2f(pin[s0 * 40 + lane]);
    acc1 += bf2f(pin[s1 * 40 + lane]);
    acc0 += bf2f(pin[s2 * 40 + lane]);
    acc1 += bf2f(pin[s3 * 40 + lane]);
  }
  for (; i < e; ++i) acc0 += bf2f(pin[srcA[i] * 40 + lane]);
  pout[node * 40 + lane] = f2bf(dis2[node] * (acc0 + acc1));
}

// final step fused with sigmoid-gate combine; covers ALL nodes
__global__ __launch_bounds__(256) void k_prop_final(
    const int* __restrict__ offs, const int* __restrict__ srcA,
    const float* __restrict__ dis, const unsigned short* __restrict__ pin,
    const int* __restrict__ mask, const float* __restrict__ hard,
    const float* __restrict__ alpha, const float* __restrict__ ft,
    float* __restrict__ outp, int n)
{
  int node = blockIdx.x * 4 + (threadIdx.x >> 6);
  if (node >= n) return;
  node = __builtin_amdgcn_readfirstlane(node);
  int lane = threadIdx.x & 63;
  if (lane >= 40) return;
  float a = 1.f / (1.f + __expf(-alpha[node]));
  float v;
  if (mask[node]){
    v = hard[(size_t)node * 40 + lane];
  } else {
    int s = offs[node], e = offs[node + 1];
    float acc0 = 0.f, acc1 = 0.f;
    int i = s;
    for (; i + 4 <= e; i += 4){
      int s0 = srcA[i], s1 = srcA[i + 1], s2 = srcA[i + 2], s3 = srcA[i + 3];
      acc0 += bf2f(pin[s0 * 40 + lane]);
      acc1 += bf2f(pin[s1 * 40 + lane]);
      acc0 += bf2f(pin[s2 * 40 + lane]);
      acc1 += bf2f(pin[s3 * 40 + lane]);
    }
    for (; i < e; ++i) acc0 += bf2f(pin[srcA[i] * 40 + lane]);
    v = dis[node] * (acc0 + acc1);
  }
  outp[(size_t)node * 40 + lane] = a * v + (1.f - a) * ft[(size_t)node * 40 + lane];
}

extern "C" void kernel_launch(void* const* d_in, const int* in_sizes, int n_in,
                              void* d_out, int out_size, void* d_ws, size_t ws_size,
                              hipStream_t stream)
{
  const float* x     = (const float*)d_in[0];
  const int*   ei    = (const int*)d_in[1];
  const float* linit = (const float*)d_in[2];
  const int*   mask  = (const int*)d_in[3];
  const float* hard  = (const float*)d_in[4];
  const float* w1    = (const float*)d_in[5];
  const float* b1    = (const float*)d_in[6];
  const float* w2    = (const float*)d_in[7];
  const float* b2    = (const float*)d_in[8];
  const float* alpha = (const float*)d_in[9];
  float* out = (float*)d_out;

  const int N   = in_sizes[3];        // 100000
  const int E   = in_sizes[1] / 2;    // 3200000
  const int K1  = in_sizes[0] / N;    // 512
  const int HID = in_sizes[6];        // 256

  char* ws = (char*)d_ws;
  size_t sXB = (size_t)N * K1 * 2;    // x_bf16 region, reused for graph arrays
  size_t sH  = (size_t)N * HID * 2;   // h_bf16 region, reused for ps buffers

  unsigned short* xb  = (unsigned short*)(ws);
  unsigned short* hb  = (unsigned short*)(ws + sXB);
  unsigned short* w1b = (unsigned short*)(ws + sXB + sH);
  unsigned short* w2p = (unsigned short*)(ws + sXB + sH + (size_t)HID * K1 * 2);
  float*          ft  = (float*)(ws + sXB + sH + (size_t)HID * K1 * 2 + 48 * 256 * 2);

  // graph arrays alias xb region (used only after gemm1 consumed xb)
  char* g = ws;
  int*   srcA = (int*)g;                      g += (size_t)(E + N) * 4;
  int*   deg  = (int*)g;                      g += (size_t)N * 4;
  int*   cnt  = (int*)g;                      g += (size_t)N * 4;
  float* dis  = (float*)g;                    g += (size_t)N * 4;
  float* dis2 = (float*)g;                    g += (size_t)N * 4;
  int*   offs = (int*)g;                      g += (size_t)(N + 64) * 4;
  int*   cur  = (int*)g;                      g += (size_t)N * 4;
  int*   bsum = (int*)g;                      g += 1024;
  int*   list = (int*)g;                      g += (size_t)N * 4;
  int*   nUn  = (int*)g;                      g += 256;

  // ps buffers alias hb region (used only after gemm2 consumed hb)
  unsigned short* psI = (unsigned short*)(ws + sXB);
  unsigned short* psA = (unsigned short*)(ws + sXB + (size_t)N * 40 * 2);
  unsigned short* psB = (unsigned short*)(ws + sXB + (size_t)N * 40 * 4);

  // 1) conversions
  k_f2bf<<<(N * K1 / 8 + 255) / 256, 256, 0, stream>>>(x, xb, N * K1);
  k_f2bf<<<(HID * K1 / 8 + 255) / 256, 256, 0, stream>>>(w1, w1b, HID * K1);
  k_w2pad<<<48, 256, 0, stream>>>(w2, w2p);

  // 2) MLP branch
  dim3 g1((N + 127) / 128, HID / 128);
  k_gemm1<<<g1, 256, 0, stream>>>(xb, w1b, b1, hb, N);
  k_gemm2<<<(N + 63) / 64, 256, 0, stream>>>(hb, w2p, b2, ft, N);

  // 3) graph prep (CSC over unmasked cols only)
  k_init0<<<(N + 255) / 256, 256, 0, stream>>>(deg, cnt, mask, nUn, N);
  k_count<<<(E / 4 + 255) / 256, 256, 0, stream>>>(ei, E, mask, deg, cnt);
  k_dis<<<(N + 255) / 256, 256, 0, stream>>>(deg, mask, dis, dis2, list, nUn, N);
  int nsb = (N + 1023) / 1024;
  k_scan1<<<nsb, 256, 0, stream>>>(cnt, offs, bsum, N);
  k_scan2<<<1, 256, 0, stream>>>(bsum, nsb, offs + N);
  k_scan3<<<nsb, 256, 0, stream>>>(offs, bsum, cur, N);
  k_scatter_e<<<(E / 4 + 255) / 256, 256, 0, stream>>>(ei, E, mask, cur, srcA);
  k_scatter_s<<<(N + 255) / 256, 256, 0, stream>>>(mask, cur, srcA, N);

  // 4) scaled-label init + 9 prop steps + fused final
  k_init_ps<<<(N * 40 + 255) / 256, 256, 0, stream>>>(linit, hard, dis, mask, psI, psA, psB, N * 40);

  const unsigned short* pin = psI;
  for (int s = 0; s < 9; ++s){
    unsigned short* po = (s & 1) ? psB : psA;
    k_prop<<<(N + 3) / 4, 256, 0, stream>>>(offs, srcA, list, nUn, dis2, pin, po);
    pin = po;
  }
  k_prop_final<<<(N + 3) / 4, 256, 0, stream>>>(offs, srcA, dis, pin, mask, hard, alpha, ft, out, N);
}